// Round 1
// baseline (114.560 us; speedup 1.0000x reference)
//
#include <hip/hip_runtime.h>

#define NRAYS 2048
#define NS    128
#define G     128
#define FC    128
#define INC   390
#define APPC  27

// mlp_in layout:
//   [0,27)    feats
//   [27,30)   vd
//   [30,192)  sin(feats * 2^f)   (d-major, f-minor, d<27, f<6)
//   [192,354) cos(feats * 2^f)
//   [354,372) sin(vd * 2^f)
//   [372,390) cos(vd * 2^f)

static __device__ __forceinline__ float tri_sample(const float* __restrict__ vol,
                                                   float gx, float gy, float gz) {
  int x0 = (int)gx; x0 = x0 < 0 ? 0 : (x0 > G - 2 ? G - 2 : x0);
  int y0 = (int)gy; y0 = y0 < 0 ? 0 : (y0 > G - 2 ? G - 2 : y0);
  int z0 = (int)gz; z0 = z0 < 0 ? 0 : (z0 > G - 2 ? G - 2 : z0);
  float fx = gx - (float)x0;
  float fy = gy - (float)y0;
  float fz = gz - (float)z0;
  const float* p = vol + ((z0 * G + y0) * G + x0);
  float v000 = p[0],       v001 = p[1];
  float v010 = p[G],       v011 = p[G + 1];
  const float* q = p + G * G;
  float v100 = q[0],       v101 = q[1];
  float v110 = q[G],       v111 = q[G + 1];
  float c00 = v000 + (v001 - v000) * fx;
  float c01 = v010 + (v011 - v010) * fx;
  float c10 = v100 + (v101 - v100) * fx;
  float c11 = v110 + (v111 - v110) * fx;
  float c0  = c00 + (c01 - c00) * fy;
  float c1  = c10 + (c11 - c10) * fy;
  return c0 + (c1 - c0) * fz;
}

// layers 2 and 3 given relu'd h1 in s_h. Block = 128 threads, one neuron each.
static __device__ __forceinline__ void mlp_tail(const float* __restrict__ W2,
                                                const float* __restrict__ b2,
                                                const float* __restrict__ W3,
                                                const float* __restrict__ b3,
                                                float* s_h, float* s_rgb, int tid) {
  float c = b2[tid];
#pragma unroll 8
  for (int k = 0; k < FC; ++k)
    c = fmaf(s_h[k], W2[k * FC + tid], c);
  __syncthreads();
  s_h[tid] = fmaxf(c, 0.0f);
  __syncthreads();
  if (tid < 3) {
    float acc = b3[tid];
#pragma unroll 8
    for (int k = 0; k < FC; ++k)
      acc = fmaf(s_h[k], W3[k * 3 + tid], acc);
    s_rgb[tid] = 1.0f / (1.0f + __expf(-acc));
  }
  __syncthreads();
}

// K0: bc[n] = b1[n] + sum of W1 rows 192..353 (the cos(0)=1 block for OOB inputs)
__global__ __launch_bounds__(FC) void k_precompute(const float* __restrict__ W1,
                                                   const float* __restrict__ b1,
                                                   float* __restrict__ bc) {
  int tid = threadIdx.x;
  float v = b1[tid];
  for (int k = 192; k < 354; ++k) v += W1[k * FC + tid];
  bc[tid] = v;
}

// K1: one block (128 threads) per ray. Exact weights + OOB MLP + base output + item append.
__global__ __launch_bounds__(128) void k_ray(const float* __restrict__ rays_o,
                                             const float* __restrict__ rays_d,
                                             const float* __restrict__ dgrid,
                                             const float* __restrict__ W1,
                                             const float* __restrict__ bc,
                                             const float* __restrict__ W2,
                                             const float* __restrict__ b2,
                                             const float* __restrict__ W3,
                                             const float* __restrict__ b3,
                                             float* __restrict__ out,
                                             float* __restrict__ dirs_ws,
                                             int* __restrict__ item_idx,
                                             float* __restrict__ item_w,
                                             int* __restrict__ counter) {
  const int ray = blockIdx.x;
  const int tid = threadIdx.x;
  __shared__ float s_alpha[NS];
  __shared__ float s_w[NS];
  __shared__ float s_h[FC];
  __shared__ float s_pe[36];
  __shared__ float s_rgb[3];
  __shared__ float s_dir[3];
  __shared__ float s_acc[1];

  if (tid == 0) {
    float dx = rays_d[ray * 3 + 0], dy = rays_d[ray * 3 + 1], dz = rays_d[ray * 3 + 2];
    float inv = rsqrtf(dx * dx + dy * dy + dz * dz);
    s_dir[0] = dx * inv; s_dir[1] = dy * inv; s_dir[2] = dz * inv;
    dirs_ws[ray * 3 + 0] = s_dir[0];
    dirs_ws[ray * 3 + 1] = s_dir[1];
    dirs_ws[ray * 3 + 2] = s_dir[2];
  }
  __syncthreads();
  const float dx = s_dir[0], dy = s_dir[1], dz = s_dir[2];
  const float ox = rays_o[ray * 3 + 0], oy = rays_o[ray * 3 + 1], oz = rays_o[ray * 3 + 2];

  // sample tid: alpha
  const float t  = 2.0f + (4.0f / 127.0f) * (float)tid;
  const float px = (ox + dx * t) * (2.0f / 3.0f);
  const float py = (oy + dy * t) * (2.0f / 3.0f);
  const float pz = (oz + dz * t) * (2.0f / 3.0f);
  const bool inb = (fabsf(px) <= 1.0f) && (fabsf(py) <= 1.0f) && (fabsf(pz) <= 1.0f);
  float sig_feat = 0.0f;
  if (inb)
    sig_feat = tri_sample(dgrid, (px + 1.0f) * 63.5f, (py + 1.0f) * 63.5f, (pz + 1.0f) * 63.5f);
  const float sigma = log1pf(__expf(sig_feat - 10.0f));
  const float alpha = 1.0f - __expf(-sigma * 0.78125f);  // delta * DISTANCE_SCALE = (4/128)*25
  s_alpha[tid] = alpha;
  __syncthreads();

  if (tid == 0) {  // exact serial transmittance scan
    float T = 1.0f, acc = 0.0f;
    for (int i = 0; i < NS; ++i) {
      float a = s_alpha[i];
      float w = a * T;
      s_w[i] = w;
      acc += w;
      T *= (1.0f - a + 1e-10f);
    }
    s_acc[0] = acc;
  }
  __syncthreads();

  const float w_self = s_w[tid];
  float woob = inb ? 0.0f : w_self;
  if (inb) {
    int slot = atomicAdd(counter, 1);
    item_idx[slot] = ray * NS + tid;
    item_w[slot]   = w_self;
  }
  s_alpha[tid] = woob;  // reuse for reduction (scan already consumed alphas)
  __syncthreads();
  for (int off = 64; off > 0; off >>= 1) {
    if (tid < off) s_alpha[tid] += s_alpha[tid + off];
    __syncthreads();
  }
  const float w_oob_sum = s_alpha[0];

  // OOB MLP: input = [0..., vd, sin=0, cos=1 (folded into bc), PE(vd)]
  if (tid < 18) {
    int d = tid / 6, f = tid % 6;
    float ang = s_dir[d] * (float)(1 << f);
    float sn, cs;
    __sincosf(ang, &sn, &cs);
    s_pe[tid]      = sn;  // input idx 354+tid
    s_pe[18 + tid] = cs;  // input idx 372+tid
  }
  __syncthreads();
  float a = bc[tid];
  a = fmaf(dx, W1[27 * FC + tid], a);
  a = fmaf(dy, W1[28 * FC + tid], a);
  a = fmaf(dz, W1[29 * FC + tid], a);
#pragma unroll
  for (int k = 0; k < 36; ++k)
    a = fmaf(s_pe[k], W1[(354 + k) * FC + tid], a);
  s_h[tid] = fmaxf(a, 0.0f);
  __syncthreads();
  mlp_tail(W2, b2, W3, b3, s_h, s_rgb, tid);

  if (tid < 3)
    out[ray * 3 + tid] = w_oob_sum * s_rgb[tid] + (1.0f - s_acc[0]);
}

// K2: full MLP for each compacted in-bounds sample. Block = 128 threads per item.
__global__ __launch_bounds__(128) void k_mlp(const float* __restrict__ rays_o,
                                             const float* __restrict__ dirs_ws,
                                             const float* __restrict__ agrid,
                                             const float* __restrict__ W1,
                                             const float* __restrict__ b1,
                                             const float* __restrict__ W2,
                                             const float* __restrict__ b2,
                                             const float* __restrict__ W3,
                                             const float* __restrict__ b3,
                                             const int* __restrict__ item_idx,
                                             const float* __restrict__ item_w,
                                             const int* __restrict__ counter,
                                             float* __restrict__ out) {
  const int tid = threadIdx.x;
  __shared__ float s_in[INC];
  __shared__ float s_h[FC];
  __shared__ float s_rgb[3];
  const int n = *counter;
  for (int it = blockIdx.x; it < n; it += gridDim.x) {
    const int idx = item_idx[it];
    const int ray = idx >> 7, s = idx & (NS - 1);
    const float w = item_w[it];
    const float dx = dirs_ws[ray * 3 + 0], dy = dirs_ws[ray * 3 + 1], dz = dirs_ws[ray * 3 + 2];
    const float t  = 2.0f + (4.0f / 127.0f) * (float)s;
    const float gx = ((rays_o[ray * 3 + 0] + dx * t) * (2.0f / 3.0f) + 1.0f) * 63.5f;
    const float gy = ((rays_o[ray * 3 + 1] + dy * t) * (2.0f / 3.0f) + 1.0f) * 63.5f;
    const float gz = ((rays_o[ray * 3 + 2] + dz * t) * (2.0f / 3.0f) + 1.0f) * 63.5f;

    if (tid < APPC)
      s_in[tid] = tri_sample(agrid + (size_t)tid * G * G * G, gx, gy, gz);
    if (tid >= 27 && tid < 30)
      s_in[tid] = (tid == 27) ? dx : ((tid == 28) ? dy : dz);
    __syncthreads();
    // PE(feats): 162 angles
    for (int a2 = tid; a2 < 162; a2 += 128) {
      int d = a2 / 6, f = a2 % 6;
      float ang = s_in[d] * (float)(1 << f);
      float sn, cs;
      __sincosf(ang, &sn, &cs);
      s_in[30 + a2]  = sn;
      s_in[192 + a2] = cs;
    }
    // PE(vd): 18 angles
    if (tid < 18) {
      int d = tid / 6, f = tid % 6;
      float v = (d == 0) ? dx : ((d == 1) ? dy : dz);
      float ang = v * (float)(1 << f);
      float sn, cs;
      __sincosf(ang, &sn, &cs);
      s_in[354 + tid] = sn;
      s_in[372 + tid] = cs;
    }
    __syncthreads();

    float a = b1[tid];
#pragma unroll 4
    for (int k = 0; k < INC; ++k)
      a = fmaf(s_in[k], W1[k * FC + tid], a);
    __syncthreads();
    s_h[tid] = fmaxf(a, 0.0f);
    __syncthreads();
    mlp_tail(W2, b2, W3, b3, s_h, s_rgb, tid);

    if (tid < 3)
      atomicAdd(&out[ray * 3 + tid], w * s_rgb[tid]);
    __syncthreads();
  }
}

// K3: clip to [0,1]
__global__ void k_clip(float* __restrict__ out) {
  int i = blockIdx.x * blockDim.x + threadIdx.x;
  if (i < NRAYS * 3) {
    float v = out[i];
    out[i] = fminf(fmaxf(v, 0.0f), 1.0f);
  }
}

extern "C" void kernel_launch(void* const* d_in, const int* in_sizes, int n_in,
                              void* d_out, int out_size, void* d_ws, size_t ws_size,
                              hipStream_t stream) {
  const float* rays_o = (const float*)d_in[0];
  const float* rays_d = (const float*)d_in[1];
  const float* dgrid  = (const float*)d_in[2];
  const float* agrid  = (const float*)d_in[3];
  const float* W1     = (const float*)d_in[4];
  const float* b1     = (const float*)d_in[5];
  const float* W2     = (const float*)d_in[6];
  const float* b2     = (const float*)d_in[7];
  const float* W3     = (const float*)d_in[8];
  const float* b3     = (const float*)d_in[9];
  float* out = (float*)d_out;

  // ws layout (bytes):
  //   [0,4)            counter (int)
  //   [256, 256+24576) dirs  (2048*3 f32)
  //   [24832, +1MB)    item_idx (262144 int, full capacity: cannot overflow)
  //   [+1MB, +2MB)     item_w   (262144 f32)
  //   [256+24576+2MB)  bc (128 f32)
  char* ws = (char*)d_ws;
  int*   counter  = (int*)(ws);
  float* dirs_ws  = (float*)(ws + 256);
  int*   item_idx = (int*)(ws + 24832);
  float* item_w   = (float*)(ws + 24832 + 1048576);
  float* bc       = (float*)(ws + 24832 + 2 * 1048576);

  hipMemsetAsync(counter, 0, sizeof(int), stream);
  hipLaunchKernelGGL(k_precompute, dim3(1), dim3(FC), 0, stream, W1, b1, bc);
  hipLaunchKernelGGL(k_ray, dim3(NRAYS), dim3(128), 0, stream,
                     rays_o, rays_d, dgrid, W1, bc, W2, b2, W3, b3,
                     out, dirs_ws, item_idx, item_w, counter);
  hipLaunchKernelGGL(k_mlp, dim3(2048), dim3(128), 0, stream,
                     rays_o, dirs_ws, agrid, W1, b1, W2, b2, W3, b3,
                     item_idx, item_w, counter, out);
  hipLaunchKernelGGL(k_clip, dim3((NRAYS * 3 + 255) / 256), dim3(256), 0, stream, out);
}

// Round 2
// 98.180 us; speedup vs baseline: 1.1668x; 1.1668x over previous
//
#include <hip/hip_runtime.h>

#define NRAYS 2048
#define NS    128
#define G     128
#define FC    128
#define INC   390
#define APPC  27
#define TILE  16

// mlp_in layout:
//   [0,27)    feats
//   [27,30)   vd
//   [30,192)  sin(feats * 2^f)   (d-major, f-minor, d<27, f<6)
//   [192,354) cos(feats * 2^f)
//   [354,372) sin(vd * 2^f)
//   [372,390) cos(vd * 2^f)

static __device__ __forceinline__ float tri_sample(const float* __restrict__ vol,
                                                   float gx, float gy, float gz) {
  int x0 = (int)gx; x0 = x0 < 0 ? 0 : (x0 > G - 2 ? G - 2 : x0);
  int y0 = (int)gy; y0 = y0 < 0 ? 0 : (y0 > G - 2 ? G - 2 : y0);
  int z0 = (int)gz; z0 = z0 < 0 ? 0 : (z0 > G - 2 ? G - 2 : z0);
  float fx = gx - (float)x0;
  float fy = gy - (float)y0;
  float fz = gz - (float)z0;
  const float* p = vol + ((z0 * G + y0) * G + x0);
  float v000 = p[0],       v001 = p[1];
  float v010 = p[G],       v011 = p[G + 1];
  const float* q = p + G * G;
  float v100 = q[0],       v101 = q[1];
  float v110 = q[G],       v111 = q[G + 1];
  float c00 = v000 + (v001 - v000) * fx;
  float c01 = v010 + (v011 - v010) * fx;
  float c10 = v100 + (v101 - v100) * fx;
  float c11 = v110 + (v111 - v110) * fx;
  float c0  = c00 + (c01 - c00) * fy;
  float c1  = c10 + (c11 - c10) * fy;
  return c0 + (c1 - c0) * fz;
}

// layers 2 and 3 given relu'd h1 in s_h. Block = 128 threads, one neuron each.
static __device__ __forceinline__ void mlp_tail(const float* __restrict__ W2,
                                                const float* __restrict__ b2,
                                                const float* __restrict__ W3,
                                                const float* __restrict__ b3,
                                                float* s_h, float* s_rgb, int tid) {
  float c = b2[tid];
#pragma unroll 8
  for (int k = 0; k < FC; ++k)
    c = fmaf(s_h[k], W2[k * FC + tid], c);
  __syncthreads();
  s_h[tid] = fmaxf(c, 0.0f);
  __syncthreads();
  if (tid < 3) {
    float acc = b3[tid];
#pragma unroll 8
    for (int k = 0; k < FC; ++k)
      acc = fmaf(s_h[k], W3[k * 3 + tid], acc);
    s_rgb[tid] = 1.0f / (1.0f + __expf(-acc));
  }
  __syncthreads();
}

// K0: bc[n] = b1[n] + sum of W1 rows 192..353 (cos(0)=1 block); also zero counter.
__global__ __launch_bounds__(FC) void k_precompute(const float* __restrict__ W1,
                                                   const float* __restrict__ b1,
                                                   float* __restrict__ bc,
                                                   int* __restrict__ counter) {
  int tid = threadIdx.x;
  if (tid == 0) *counter = 0;
  float v = b1[tid];
  for (int k = 192; k < 354; ++k) v += W1[k * FC + tid];
  bc[tid] = v;
}

// K1: one block (128 threads) per ray. Exact weights + OOB MLP + base output + item append.
__global__ __launch_bounds__(128) void k_ray(const float* __restrict__ rays_o,
                                             const float* __restrict__ rays_d,
                                             const float* __restrict__ dgrid,
                                             const float* __restrict__ W1,
                                             const float* __restrict__ bc,
                                             const float* __restrict__ W2,
                                             const float* __restrict__ b2,
                                             const float* __restrict__ W3,
                                             const float* __restrict__ b3,
                                             float* __restrict__ out,
                                             float* __restrict__ dirs_ws,
                                             int* __restrict__ item_idx,
                                             float* __restrict__ item_w,
                                             int* __restrict__ counter) {
  const int ray = blockIdx.x;
  const int tid = threadIdx.x;
  __shared__ float s_alpha[NS];
  __shared__ float s_w[NS];
  __shared__ float s_h[FC];
  __shared__ float s_pe[36];
  __shared__ float s_rgb[3];
  __shared__ float s_dir[3];
  __shared__ float s_acc[1];

  if (tid == 0) {
    float dx = rays_d[ray * 3 + 0], dy = rays_d[ray * 3 + 1], dz = rays_d[ray * 3 + 2];
    float inv = rsqrtf(dx * dx + dy * dy + dz * dz);
    s_dir[0] = dx * inv; s_dir[1] = dy * inv; s_dir[2] = dz * inv;
    dirs_ws[ray * 3 + 0] = s_dir[0];
    dirs_ws[ray * 3 + 1] = s_dir[1];
    dirs_ws[ray * 3 + 2] = s_dir[2];
  }
  __syncthreads();
  const float dx = s_dir[0], dy = s_dir[1], dz = s_dir[2];
  const float ox = rays_o[ray * 3 + 0], oy = rays_o[ray * 3 + 1], oz = rays_o[ray * 3 + 2];

  const float t  = 2.0f + (4.0f / 127.0f) * (float)tid;
  const float px = (ox + dx * t) * (2.0f / 3.0f);
  const float py = (oy + dy * t) * (2.0f / 3.0f);
  const float pz = (oz + dz * t) * (2.0f / 3.0f);
  const bool inb = (fabsf(px) <= 1.0f) && (fabsf(py) <= 1.0f) && (fabsf(pz) <= 1.0f);
  float sig_feat = 0.0f;
  if (inb)
    sig_feat = tri_sample(dgrid, (px + 1.0f) * 63.5f, (py + 1.0f) * 63.5f, (pz + 1.0f) * 63.5f);
  const float sigma = log1pf(__expf(sig_feat - 10.0f));
  const float alpha = 1.0f - __expf(-sigma * 0.78125f);  // delta * DISTANCE_SCALE
  s_alpha[tid] = alpha;
  __syncthreads();

  if (tid == 0) {  // exact serial transmittance scan
    float T = 1.0f, acc = 0.0f;
    for (int i = 0; i < NS; ++i) {
      float a = s_alpha[i];
      float w = a * T;
      s_w[i] = w;
      acc += w;
      T *= (1.0f - a + 1e-10f);
    }
    s_acc[0] = acc;
  }
  __syncthreads();

  const float w_self = s_w[tid];
  float woob = inb ? 0.0f : w_self;
  if (inb) {
    int slot = atomicAdd(counter, 1);
    item_idx[slot] = ray * NS + tid;
    item_w[slot]   = w_self;
  }
  s_alpha[tid] = woob;
  __syncthreads();
  for (int off = 64; off > 0; off >>= 1) {
    if (tid < off) s_alpha[tid] += s_alpha[tid + off];
    __syncthreads();
  }
  const float w_oob_sum = s_alpha[0];

  // OOB MLP: input = [0..., vd, sin=0, cos=1 (folded into bc), PE(vd)]
  if (tid < 18) {
    int d = tid / 6, f = tid % 6;
    float ang = s_dir[d] * (float)(1 << f);
    float sn, cs;
    __sincosf(ang, &sn, &cs);
    s_pe[tid]      = sn;
    s_pe[18 + tid] = cs;
  }
  __syncthreads();
  float a = bc[tid];
  a = fmaf(dx, W1[27 * FC + tid], a);
  a = fmaf(dy, W1[28 * FC + tid], a);
  a = fmaf(dz, W1[29 * FC + tid], a);
#pragma unroll
  for (int k = 0; k < 36; ++k)
    a = fmaf(s_pe[k], W1[(354 + k) * FC + tid], a);
  s_h[tid] = fmaxf(a, 0.0f);
  __syncthreads();
  mlp_tail(W2, b2, W3, b3, s_h, s_rgb, tid);

  if (tid < 3)
    out[ray * 3 + tid] = w_oob_sum * s_rgb[tid] + (1.0f - s_acc[0]);
}

// K2 v2: batched MLP — 16 items per 256-thread block. Weights read once per tile.
__global__ __launch_bounds__(256) void k_mlp(const float* __restrict__ rays_o,
                                             const float* __restrict__ dirs_ws,
                                             const float* __restrict__ agrid,
                                             const float* __restrict__ W1,
                                             const float* __restrict__ b1,
                                             const float* __restrict__ W2,
                                             const float* __restrict__ b2,
                                             const float* __restrict__ W3,
                                             const float* __restrict__ b3,
                                             const int* __restrict__ item_idx,
                                             const float* __restrict__ item_w,
                                             const int* __restrict__ counter,
                                             float* __restrict__ out) {
  const int tid = threadIdx.x;
  __shared__ float s_inT[INC][TILE];   // [k][item], 24.4 KB. reused as h2 (stride 20) later
  __shared__ float s_hT[FC][20];       // [neuron][item], padded stride 20 -> 10 KB
  __shared__ int   s_ray[TILE];
  __shared__ float s_w[TILE];
  __shared__ float s_gx[TILE], s_gy[TILE], s_gz[TILE];

  const int n = *counter;
  const int nrn = tid & 127;   // neuron
  const int j0  = (tid >> 7) * 8;  // item sub-block: 0 or 8

  for (int base = blockIdx.x * TILE; base < n; base += gridDim.x * TILE) {
    const int nt = (n - base < TILE) ? (n - base) : TILE;

    if (tid < TILE) {
      const int j = tid;
      if (j < nt) {
        const int idx = item_idx[base + j];
        const int ray = idx >> 7, s = idx & (NS - 1);
        s_ray[j] = ray;
        s_w[j]   = item_w[base + j];
        const float dx = dirs_ws[ray * 3 + 0], dy = dirs_ws[ray * 3 + 1], dz = dirs_ws[ray * 3 + 2];
        const float t  = 2.0f + (4.0f / 127.0f) * (float)s;
        s_gx[j] = ((rays_o[ray * 3 + 0] + dx * t) * (2.0f / 3.0f) + 1.0f) * 63.5f;
        s_gy[j] = ((rays_o[ray * 3 + 1] + dy * t) * (2.0f / 3.0f) + 1.0f) * 63.5f;
        s_gz[j] = ((rays_o[ray * 3 + 2] + dz * t) * (2.0f / 3.0f) + 1.0f) * 63.5f;
        s_inT[27][j] = dx; s_inT[28][j] = dy; s_inT[29][j] = dz;
      } else {
        s_ray[j] = -1; s_w[j] = 0.0f;
        s_gx[j] = 0.0f; s_gy[j] = 0.0f; s_gz[j] = 0.0f;
        s_inT[27][j] = 0.0f; s_inT[28][j] = 0.0f; s_inT[29][j] = 0.0f;
      }
    }
    __syncthreads();

    // feats: 27 channels x 16 items
    for (int a = tid; a < APPC * TILE; a += 256) {
      const int j = a & (TILE - 1), c = a >> 4;
      s_inT[c][j] = (j < nt) ? tri_sample(agrid + (size_t)c * G * G * G, s_gx[j], s_gy[j], s_gz[j])
                             : 0.0f;
    }
    __syncthreads();

    // PE(feats): 162 angles x 16 items
    for (int a = tid; a < 162 * TILE; a += 256) {
      const int j = a & (TILE - 1), idx = a >> 4;
      const int d = idx / 6, f = idx % 6;
      float ang = s_inT[d][j] * (float)(1 << f);
      float sn, cs;
      __sincosf(ang, &sn, &cs);
      s_inT[30 + idx][j]  = sn;
      s_inT[192 + idx][j] = cs;
    }
    // PE(vd): 18 angles x 16 items (reads rows 27..29, writes 354+ — disjoint)
    for (int a = tid; a < 18 * TILE; a += 256) {
      const int j = a & (TILE - 1), idx = a >> 4;
      const int d = idx / 6, f = idx % 6;
      float ang = s_inT[27 + d][j] * (float)(1 << f);
      float sn, cs;
      __sincosf(ang, &sn, &cs);
      s_inT[354 + idx][j] = sn;
      s_inT[372 + idx][j] = cs;
    }
    __syncthreads();

    // layer 1: thread = (neuron nrn, items j0..j0+7)
    float acc[8];
    {
      const float bb = b1[nrn];
#pragma unroll
      for (int i = 0; i < 8; ++i) acc[i] = bb;
    }
#pragma unroll 2
    for (int k = 0; k < INC; ++k) {
      const float w = W1[k * FC + nrn];
      const float4 v0 = *(const float4*)&s_inT[k][j0];
      const float4 v1 = *(const float4*)&s_inT[k][j0 + 4];
      acc[0] = fmaf(v0.x, w, acc[0]);
      acc[1] = fmaf(v0.y, w, acc[1]);
      acc[2] = fmaf(v0.z, w, acc[2]);
      acc[3] = fmaf(v0.w, w, acc[3]);
      acc[4] = fmaf(v1.x, w, acc[4]);
      acc[5] = fmaf(v1.y, w, acc[5]);
      acc[6] = fmaf(v1.z, w, acc[6]);
      acc[7] = fmaf(v1.w, w, acc[7]);
    }
#pragma unroll
    for (int i = 0; i < 8; ++i) s_hT[nrn][j0 + i] = fmaxf(acc[i], 0.0f);
    __syncthreads();

    // layer 2
    float acc2[8];
    {
      const float bb = b2[nrn];
#pragma unroll
      for (int i = 0; i < 8; ++i) acc2[i] = bb;
    }
#pragma unroll 2
    for (int k = 0; k < FC; ++k) {
      const float w = W2[k * FC + nrn];
      const float4 u0 = *(const float4*)&s_hT[k][j0];
      const float4 u1 = *(const float4*)&s_hT[k][j0 + 4];
      acc2[0] = fmaf(u0.x, w, acc2[0]);
      acc2[1] = fmaf(u0.y, w, acc2[1]);
      acc2[2] = fmaf(u0.z, w, acc2[2]);
      acc2[3] = fmaf(u0.w, w, acc2[3]);
      acc2[4] = fmaf(u1.x, w, acc2[4]);
      acc2[5] = fmaf(u1.y, w, acc2[5]);
      acc2[6] = fmaf(u1.z, w, acc2[6]);
      acc2[7] = fmaf(u1.w, w, acc2[7]);
    }
    __syncthreads();   // all s_inT reads (layer1) done well before; this orders h2 overwrite vs layer2 reads of s_hT? (s_hT reads above are done per-thread; barrier ensures tile-wide)
    float* s_h2 = &s_inT[0][0];  // reuse as [128][20] padded
#pragma unroll
    for (int i = 0; i < 8; ++i) s_h2[nrn * 20 + j0 + i] = fmaxf(acc2[i], 0.0f);
    __syncthreads();

    // layer 3 + composite
    if (tid < 3 * TILE) {
      const int j = tid / 3, c = tid % 3;
      if (j < nt) {
        float a3 = b3[c];
#pragma unroll 8
        for (int k = 0; k < FC; ++k)
          a3 = fmaf(s_h2[k * 20 + j], W3[k * 3 + c], a3);
        const float rgb = 1.0f / (1.0f + __expf(-a3));
        atomicAdd(&out[s_ray[j] * 3 + c], s_w[j] * rgb);
      }
    }
    __syncthreads();  // protect s_* reuse next tile
  }
}

// K3: clip to [0,1]
__global__ void k_clip(float* __restrict__ out) {
  int i = blockIdx.x * blockDim.x + threadIdx.x;
  if (i < NRAYS * 3) {
    float v = out[i];
    out[i] = fminf(fmaxf(v, 0.0f), 1.0f);
  }
}

extern "C" void kernel_launch(void* const* d_in, const int* in_sizes, int n_in,
                              void* d_out, int out_size, void* d_ws, size_t ws_size,
                              hipStream_t stream) {
  const float* rays_o = (const float*)d_in[0];
  const float* rays_d = (const float*)d_in[1];
  const float* dgrid  = (const float*)d_in[2];
  const float* agrid  = (const float*)d_in[3];
  const float* W1     = (const float*)d_in[4];
  const float* b1     = (const float*)d_in[5];
  const float* W2     = (const float*)d_in[6];
  const float* b2     = (const float*)d_in[7];
  const float* W3     = (const float*)d_in[8];
  const float* b3     = (const float*)d_in[9];
  float* out = (float*)d_out;

  char* ws = (char*)d_ws;
  int*   counter  = (int*)(ws);
  float* dirs_ws  = (float*)(ws + 256);
  int*   item_idx = (int*)(ws + 24832);
  float* item_w   = (float*)(ws + 24832 + 1048576);
  float* bc       = (float*)(ws + 24832 + 2 * 1048576);

  hipLaunchKernelGGL(k_precompute, dim3(1), dim3(FC), 0, stream, W1, b1, bc, counter);
  hipLaunchKernelGGL(k_ray, dim3(NRAYS), dim3(128), 0, stream,
                     rays_o, rays_d, dgrid, W1, bc, W2, b2, W3, b3,
                     out, dirs_ws, item_idx, item_w, counter);
  hipLaunchKernelGGL(k_mlp, dim3(512), dim3(256), 0, stream,
                     rays_o, dirs_ws, agrid, W1, b1, W2, b2, W3, b3,
                     item_idx, item_w, counter, out);
  hipLaunchKernelGGL(k_clip, dim3((NRAYS * 3 + 255) / 256), dim3(256), 0, stream, out);
}